// Round 3
// baseline (318.977 us; speedup 1.0000x reference)
//
#include <hip/hip_runtime.h>
#include <hip/hip_bf16.h>

#define NB   4
#define CCH  256
#define CQK  32
#define NTOK 4096
#define LOG2E 1.4426950408889634f

typedef unsigned short u16;
typedef unsigned int   u32;
typedef __attribute__((ext_vector_type(8))) __bf16 bf16x8;
typedef __attribute__((ext_vector_type(4))) float  f32x4;

union bfu { bf16x8 v; u16 s[8]; };

static __device__ __forceinline__ u16 f2bf(float f) {
  union { __hip_bfloat16 h; u16 u; } c; c.h = __float2bfloat16(f); return c.u;
}
static __device__ __forceinline__ float bf2f(u16 u) {
  union { __hip_bfloat16 h; u16 u; } c; c.u = u; return __bfloat162float(c.h);
}
static __device__ __forceinline__ u32 f2bf2(float a, float b) {
  union { __hip_bfloat162 h; u32 u; } cv;
  cv.h = __float22bfloat162_rn(make_float2(a, b));
  return cv.u;
}
static __device__ __forceinline__ f32x4 mfma16(bf16x8 a, bf16x8 b, f32x4 c) {
  return __builtin_amdgcn_mfma_f32_16x16x32_bf16(a, b, c, 0, 0, 0);
}

// ---------------- Kernel 0: split W to bf16 hi/lo (once, tiny) ----------------
// W rows: 0-31 = wq (pre-scaled by log2e), 32-63 = wk, 64-319 = wv.
__global__ __launch_bounds__(256) void convert_w(
    const float* __restrict__ wq, const float* __restrict__ wk,
    const float* __restrict__ wv, u16* __restrict__ whi, u16* __restrict__ wlo)
{
  int i   = blockIdx.x * 256 + threadIdx.x;  // float4 index, 320*64 total
  int row = i >> 6;
  int col = (i & 63) * 4;
  const float* src = (row < 32) ? wq + row * CCH
                   : (row < 64) ? wk + (row - 32) * CCH
                                : wv + (row - 64) * CCH;
  float sc = (row < 32) ? LOG2E : 1.0f;
  float4 v = *(const float4*)(src + col);
  float f[4] = { v.x * sc, v.y * sc, v.z * sc, v.w * sc };
  u16 h[4], l[4];
#pragma unroll
  for (int j = 0; j < 4; j++) {
    h[j] = f2bf(f[j]);
    l[j] = f2bf(f[j] - bf2f(h[j]));
  }
  uint2 ph = { (u32)h[0] | ((u32)h[1] << 16), (u32)h[2] | ((u32)h[3] << 16) };
  uint2 pl = { (u32)l[0] | ((u32)l[1] << 16), (u32)l[2] | ((u32)l[3] << 16) };
  *(uint2*)(whi + (size_t)i * 4) = ph;
  *(uint2*)(wlo + (size_t)i * 4) = pl;
}

// ---------------- Kernel 1: MFMA QKV projection ----------------
// Block: 256 thr / 4 waves, n-tile 32, grid (128, NB). No LDS.
// 3-term split MFMA: Whi*xhi + Whi*xlo + Wlo*xhi (error ~2^-18).
// Wave w owns o-tiles {w, w+4, w+8, w+12, w+16}: tile 0 = Q/K rows, rest = V.
__global__ __launch_bounds__(256, 2) void qkv_proj(
    const float* __restrict__ x,
    const float* __restrict__ bq, const float* __restrict__ bk,
    const float* __restrict__ bv,
    const u16* __restrict__ whi, const u16* __restrict__ wlo,
    u16* __restrict__ Qo, u16* __restrict__ Ko, u16* __restrict__ Vo)
{
  const int nt = blockIdx.x;
  const int b  = blockIdx.y;
  const int n0 = nt * 32;
  const int tid = threadIdx.x;
  const int w = tid >> 6, lane = tid & 63, lo = lane & 15, hi = lane >> 4;

  const f32x4 fz = { 0.f, 0.f, 0.f, 0.f };
  f32x4 acc[5][2];
#pragma unroll
  for (int t = 0; t < 5; t++) { acc[t][0] = fz; acc[t][1] = fz; }

  const float* xb = x + (size_t)b * CCH * NTOK;

  for (int k = 0; k < 8; k++) {
    const int ck = k * 32;
    // x fragments (identical across waves -> L1 broadcast); hi/lo split.
    bf16x8 xh[2], xl[2];
#pragma unroll
    for (int nt2 = 0; nt2 < 2; nt2++) {
      const float* xc = xb + (size_t)(ck + hi * 8) * NTOK + n0 + nt2 * 16 + lo;
      bfu H, L;
#pragma unroll
      for (int j = 0; j < 8; j++) {
        float f  = xc[(size_t)j * NTOK];
        u16  hh  = f2bf(f);
        H.s[j] = hh;
        L.s[j] = f2bf(f - bf2f(hh));
      }
      xh[nt2] = H.v; xl[nt2] = L.v;
    }
#pragma unroll
    for (int t = 0; t < 5; t++) {
      const int ot = w + t * 4;
      const size_t woff = (size_t)(ot * 16 + lo) * CCH + ck + hi * 8;
      bf16x8 wh = *(const bf16x8*)(whi + woff);
      bf16x8 wl = *(const bf16x8*)(wlo + woff);
#pragma unroll
      for (int nt2 = 0; nt2 < 2; nt2++) {
        if (t == 0) {   // Q/K: D[row=o][col=n]
          acc[t][nt2] = mfma16(wh, xh[nt2], acc[t][nt2]);
          acc[t][nt2] = mfma16(wh, xl[nt2], acc[t][nt2]);
          acc[t][nt2] = mfma16(wl, xh[nt2], acc[t][nt2]);
        } else {        // V: D[row=n][col=c]
          acc[t][nt2] = mfma16(xh[nt2], wh, acc[t][nt2]);
          acc[t][nt2] = mfma16(xl[nt2], wh, acc[t][nt2]);
          acc[t][nt2] = mfma16(xh[nt2], wl, acc[t][nt2]);
        }
      }
    }
  }

  // Epilogue: o-tile 0 -> Q (w<2) or K rows, d = (w&1)*16 + 4hi + r.
  {
    const float* bsrc = (w < 2) ? bq : bk;
    const float  sc   = (w < 2) ? LOG2E : 1.0f;
    float4 b4 = *(const float4*)(bsrc + (w & 1) * 16 + hi * 4);
    float b0 = b4.x * sc, b1 = b4.y * sc, b2 = b4.z * sc, b3 = b4.w * sc;
    u16* base = (w < 2) ? Qo : Ko;
#pragma unroll
    for (int nt2 = 0; nt2 < 2; nt2++) {
      int n = n0 + nt2 * 16 + lo;
      f32x4 a = acc[0][nt2];
      uint2 pk = { f2bf2(a[0] + b0, a[1] + b1), f2bf2(a[2] + b2, a[3] + b3) };
      *(uint2*)(base + ((size_t)b * NTOK + n) * CQK + (w & 1) * 16 + hi * 4) = pk;
    }
  }
  // V tiles: c = (ot-4)*16 + lo, n = n0 + nt2*16 + 4hi + r.
#pragma unroll
  for (int t = 1; t < 5; t++) {
    int c = (w + t * 4 - 4) * 16 + lo;
    float bvc = bv[c];
#pragma unroll
    for (int nt2 = 0; nt2 < 2; nt2++) {
      f32x4 a = acc[t][nt2];
      uint2 pk = { f2bf2(a[0] + bvc, a[1] + bvc), f2bf2(a[2] + bvc, a[3] + bvc) };
      *(uint2*)(Vo + ((size_t)b * CCH + c) * NTOK + n0 + nt2 * 16 + hi * 4) = pk;
    }
  }
}

// ---------------- Kernel 2: barrier-free per-wave flash attention ----------------
// Grid 1024 x 256 thr (4 waves) -> 4 blocks/CU = 16 waves/CU. Each wave:
// independent job (b, 16 queries, 64 channels); softmax(ch+1) pipelined
// against PV(ch); P transposed via wave-private LDS (lgkmcnt only, no barriers).
__global__ __launch_bounds__(256, 4) void attn(
    const float* __restrict__ x,
    const u16* __restrict__ Qm, const u16* __restrict__ Km,
    const u16* __restrict__ Vm, float* __restrict__ out)
{
  const int g    = blockIdx.x;
  const int lw3  = g & 7;
  const int b    = lw3 >> 1;                    // XCD pair per batch
  const int rest = ((g >> 3) << 1) | (lw3 & 1); // 0..255
  const int cq   = rest & 3;
  const int qg   = rest >> 2;

  const int tid = threadIdx.x;
  const int w = tid >> 6, lane = tid & 63, lo = lane & 15, hi = lane >> 4;
  const int q0 = qg * 64 + w * 16;
  const int c0 = cq * 64;

  __shared__ u16   P_scr[4][2][16][72];
  __shared__ float a_scr[4][2][16];
  __shared__ float l_scr[4][16];

  const f32x4 fz = { 0.f, 0.f, 0.f, 0.f };
  bf16x8 qf = *(const bf16x8*)(Qm + ((size_t)b * NTOK + q0 + lo) * CQK + hi * 8);

  f32x4 acc[4] = { fz, fz, fz, fz };
  float m_run = -INFINITY, l_run = 0.f;
  const u16* Kb = Km + (size_t)b * NTOK * CQK;
  const u16* Vb = Vm + (size_t)b * CCH * NTOK + (size_t)(c0 + lo) * NTOK + hi * 8;

  bf16x8 kf[4];
  auto ld_k = [&](int ch) {
#pragma unroll
    for (int mt = 0; mt < 4; mt++)
      kf[mt] = *(const bf16x8*)(Kb + (size_t)(ch * 64 + mt * 16 + lo) * CQK + hi * 8);
  };

  // S^T = mfma(K,Q): lane holds n=lo, m = 16mt+4hi+r -> per-lane softmax.
  auto softmax_chunk = [&](int nb) {
    f32x4 s[4];
#pragma unroll
    for (int mt = 0; mt < 4; mt++) s[mt] = mfma16(kf[mt], qf, fz);
    float cm = -INFINITY;
#pragma unroll
    for (int mt = 0; mt < 4; mt++)
#pragma unroll
      for (int r = 0; r < 4; r++) cm = fmaxf(cm, s[mt][r]);
    cm = fmaxf(cm, __shfl_xor(cm, 16));
    cm = fmaxf(cm, __shfl_xor(cm, 32));
    float mnew  = fmaxf(m_run, cm);
    float alpha = __builtin_amdgcn_exp2f(m_run - mnew);
    float ps = 0.f;
    u32 pw[4][2];
#pragma unroll
    for (int mt = 0; mt < 4; mt++) {
      float p0 = __builtin_amdgcn_exp2f(s[mt][0] - mnew);
      float p1 = __builtin_amdgcn_exp2f(s[mt][1] - mnew);
      float p2 = __builtin_amdgcn_exp2f(s[mt][2] - mnew);
      float p3 = __builtin_amdgcn_exp2f(s[mt][3] - mnew);
      ps += (p0 + p1) + (p2 + p3);
      pw[mt][0] = f2bf2(p0, p1);
      pw[mt][1] = f2bf2(p2, p3);
    }
    ps += __shfl_xor(ps, 16);
    ps += __shfl_xor(ps, 32);
    l_run = l_run * alpha + ps;
    m_run = mnew;
    u16* prow = &P_scr[w][nb][lo][0];
#pragma unroll
    for (int mt = 0; mt < 4; mt++) {
      *(u32*)(prow + mt * 16 + hi * 4)     = pw[mt][0];
      *(u32*)(prow + mt * 16 + hi * 4 + 2) = pw[mt][1];
    }
    if (hi == 0) a_scr[w][nb][lo] = alpha;
  };

  // Prologue: softmax(0) into buf 0; K for chunk 1 in regs.
  ld_k(0);
  softmax_chunk(0);
  ld_k(1);

  for (int ch = 0; ch < 64; ch++) {
    const int    buf  = ch & 1;
    const size_t moff = (size_t)ch * 64;

    bf16x8 vf0[4];
#pragma unroll
    for (int cj = 0; cj < 4; cj++)
      vf0[cj] = *(const bf16x8*)(Vb + (size_t)cj * 16 * NTOK + moff);

    // P/alpha reads for PV(ch) issued BEFORE softmax writes buf^1 (FIFO-safe).
    bf16x8 af0 = *(const bf16x8*)&P_scr[w][buf][lo][hi * 8];
    bf16x8 af1 = *(const bf16x8*)&P_scr[w][buf][lo][32 + hi * 8];
    f32x4  al  = *(const f32x4*)&a_scr[w][buf][hi * 4];

    if (ch + 1 < 64) {
      softmax_chunk(buf ^ 1);
      if (ch + 2 < 64) ld_k(ch + 2);
    }

    bf16x8 vf1[4];
#pragma unroll
    for (int cj = 0; cj < 4; cj++)
      vf1[cj] = *(const bf16x8*)(Vb + (size_t)cj * 16 * NTOK + moff + 32);

#pragma unroll
    for (int cj = 0; cj < 4; cj++) {
      acc[cj][0] *= al[0]; acc[cj][1] *= al[1];
      acc[cj][2] *= al[2]; acc[cj][3] *= al[3];
    }
#pragma unroll
    for (int cj = 0; cj < 4; cj++) {
      acc[cj] = mfma16(af0, vf0[cj], acc[cj]);
      acc[cj] = mfma16(af1, vf1[cj], acc[cj]);
    }
  }

  // Epilogue: gather l per output row (q = q0 + 4hi + r), normalize, +x.
  if (hi == 0) l_scr[w][lo] = l_run;
  f32x4 lv = *(const f32x4*)&l_scr[w][hi * 4];
  f32x4 il = { 1.f / lv[0], 1.f / lv[1], 1.f / lv[2], 1.f / lv[3] };

  const float* xb2 = x   + (size_t)b * CCH * NTOK;
  float*       ob  = out + (size_t)b * CCH * NTOK;
#pragma unroll
  for (int cj = 0; cj < 4; cj++) {
    int c = c0 + cj * 16 + lo;
    size_t base = (size_t)c * NTOK + q0 + hi * 4;
    float4 xr = *(const float4*)(xb2 + base);
    float4 o;
    o.x = acc[cj][0] * il[0] + xr.x;
    o.y = acc[cj][1] * il[1] + xr.y;
    o.z = acc[cj][2] * il[2] + xr.z;
    o.w = acc[cj][3] * il[3] + xr.w;
    *(float4*)(ob + base) = o;
  }
}

extern "C" void kernel_launch(void* const* d_in, const int* in_sizes, int n_in,
                              void* d_out, int out_size, void* d_ws, size_t ws_size,
                              hipStream_t stream) {
  const float* x  = (const float*)d_in[0];
  const float* wq = (const float*)d_in[1];
  const float* bq = (const float*)d_in[2];
  const float* wk = (const float*)d_in[3];
  const float* bk = (const float*)d_in[4];
  const float* wv = (const float*)d_in[5];
  const float* bv = (const float*)d_in[6];
  float* out = (float*)d_out;

  // ws (bf16): Q [4,4096,32] | K [4,4096,32] | V [4,256,4096] | Whi,Wlo [320,256]
  u16* Qp  = (u16*)d_ws;
  u16* Kp  = Qp + (size_t)NB * NTOK * CQK;
  u16* Vp  = Kp + (size_t)NB * NTOK * CQK;
  u16* Whi = Vp + (size_t)NB * CCH * NTOK;
  u16* Wlo = Whi + (size_t)320 * CCH;

  convert_w<<<80, 256, 0, stream>>>(wq, wk, wv, Whi, Wlo);
  dim3 pg(128, NB);
  qkv_proj<<<pg, 256, 0, stream>>>(x, bq, bk, bv, Whi, Wlo, Qp, Kp, Vp);
  attn<<<1024, 256, 0, stream>>>(x, Qp, Kp, Vp, out);
}

// Round 4
// 135.694 us; speedup vs baseline: 2.3507x; 2.3507x over previous
//
#include <hip/hip_runtime.h>
#include <hip/hip_bf16.h>

#define NB   4
#define CCH  256
#define CQK  32
#define NTOK 4096
#define LOG2E 1.4426950408889634f

typedef unsigned short u16;
typedef unsigned int   u32;
typedef __attribute__((ext_vector_type(8))) __bf16 bf16x8;
typedef __attribute__((ext_vector_type(4))) float  f32x4;

union bfu { bf16x8 v; u16 s[8]; };

static __device__ __forceinline__ u16 f2bf(float f) {
  union { __hip_bfloat16 h; u16 u; } c; c.h = __float2bfloat16(f); return c.u;
}
static __device__ __forceinline__ float bf2f(u16 u) {
  union { __hip_bfloat16 h; u16 u; } c; c.u = u; return __bfloat162float(c.h);
}
static __device__ __forceinline__ u32 f2bf2(float a, float b) {
  union { __hip_bfloat162 h; u32 u; } cv;
  cv.h = __float22bfloat162_rn(make_float2(a, b));
  return cv.u;
}
static __device__ __forceinline__ f32x4 mfma16(bf16x8 a, bf16x8 b, f32x4 c) {
  return __builtin_amdgcn_mfma_f32_16x16x32_bf16(a, b, c, 0, 0, 0);
}

// ---------------- Kernel 0: split W to bf16 hi/lo (once, tiny) ----------------
__global__ __launch_bounds__(256) void convert_w(
    const float* __restrict__ wq, const float* __restrict__ wk,
    const float* __restrict__ wv, u16* __restrict__ whi, u16* __restrict__ wlo)
{
  int i   = blockIdx.x * 256 + threadIdx.x;  // float4 index, 320*64 total
  int row = i >> 6;
  int col = (i & 63) * 4;
  const float* src = (row < 32) ? wq + row * CCH
                   : (row < 64) ? wk + (row - 32) * CCH
                                : wv + (row - 64) * CCH;
  float sc = (row < 32) ? LOG2E : 1.0f;
  float4 v = *(const float4*)(src + col);
  float f[4] = { v.x * sc, v.y * sc, v.z * sc, v.w * sc };
  u16 h[4], l[4];
#pragma unroll
  for (int j = 0; j < 4; j++) {
    h[j] = f2bf(f[j]);
    l[j] = f2bf(f[j] - bf2f(h[j]));
  }
  uint2 ph = { (u32)h[0] | ((u32)h[1] << 16), (u32)h[2] | ((u32)h[3] << 16) };
  uint2 pl = { (u32)l[0] | ((u32)l[1] << 16), (u32)l[2] | ((u32)l[3] << 16) };
  *(uint2*)(whi + (size_t)i * 4) = ph;
  *(uint2*)(wlo + (size_t)i * 4) = pl;
}

// ---------------- Kernel 1: MFMA QKV projection ----------------
__global__ __launch_bounds__(256, 2) void qkv_proj(
    const float* __restrict__ x,
    const float* __restrict__ bq, const float* __restrict__ bk,
    const float* __restrict__ bv,
    const u16* __restrict__ whi, const u16* __restrict__ wlo,
    u16* __restrict__ Qo, u16* __restrict__ Ko, u16* __restrict__ Vo)
{
  const int nt = blockIdx.x;
  const int b  = blockIdx.y;
  const int n0 = nt * 32;
  const int tid = threadIdx.x;
  const int w = tid >> 6, lane = tid & 63, lo = lane & 15, hi = lane >> 4;

  const f32x4 fz = { 0.f, 0.f, 0.f, 0.f };
  f32x4 acc[5][2];
#pragma unroll
  for (int t = 0; t < 5; t++) { acc[t][0] = fz; acc[t][1] = fz; }

  const float* xb = x + (size_t)b * CCH * NTOK;

  for (int k = 0; k < 8; k++) {
    const int ck = k * 32;
    bf16x8 xh[2], xl[2];
#pragma unroll
    for (int nt2 = 0; nt2 < 2; nt2++) {
      const float* xc = xb + (size_t)(ck + hi * 8) * NTOK + n0 + nt2 * 16 + lo;
      bfu H, L;
#pragma unroll
      for (int j = 0; j < 8; j++) {
        float f  = xc[(size_t)j * NTOK];
        u16  hh  = f2bf(f);
        H.s[j] = hh;
        L.s[j] = f2bf(f - bf2f(hh));
      }
      xh[nt2] = H.v; xl[nt2] = L.v;
    }
#pragma unroll
    for (int t = 0; t < 5; t++) {
      const int ot = w + t * 4;
      const size_t woff = (size_t)(ot * 16 + lo) * CCH + ck + hi * 8;
      bf16x8 wh = *(const bf16x8*)(whi + woff);
      bf16x8 wl = *(const bf16x8*)(wlo + woff);
#pragma unroll
      for (int nt2 = 0; nt2 < 2; nt2++) {
        if (t == 0) {   // Q/K: D[row=o][col=n]
          acc[t][nt2] = mfma16(wh, xh[nt2], acc[t][nt2]);
          acc[t][nt2] = mfma16(wh, xl[nt2], acc[t][nt2]);
          acc[t][nt2] = mfma16(wl, xh[nt2], acc[t][nt2]);
        } else {        // V: D[row=n][col=c]
          acc[t][nt2] = mfma16(xh[nt2], wh, acc[t][nt2]);
          acc[t][nt2] = mfma16(xl[nt2], wh, acc[t][nt2]);
          acc[t][nt2] = mfma16(xh[nt2], wl, acc[t][nt2]);
        }
      }
    }
  }

  {
    const float* bsrc = (w < 2) ? bq : bk;
    const float  sc   = (w < 2) ? LOG2E : 1.0f;
    float4 b4 = *(const float4*)(bsrc + (w & 1) * 16 + hi * 4);
    float b0 = b4.x * sc, b1 = b4.y * sc, b2 = b4.z * sc, b3 = b4.w * sc;
    u16* base = (w < 2) ? Qo : Ko;
#pragma unroll
    for (int nt2 = 0; nt2 < 2; nt2++) {
      int n = n0 + nt2 * 16 + lo;
      f32x4 a = acc[0][nt2];
      uint2 pk = { f2bf2(a[0] + b0, a[1] + b1), f2bf2(a[2] + b2, a[3] + b3) };
      *(uint2*)(base + ((size_t)b * NTOK + n) * CQK + (w & 1) * 16 + hi * 4) = pk;
    }
  }
#pragma unroll
  for (int t = 1; t < 5; t++) {
    int c = (w + t * 4 - 4) * 16 + lo;
    float bvc = bv[c];
#pragma unroll
    for (int nt2 = 0; nt2 < 2; nt2++) {
      f32x4 a = acc[t][nt2];
      uint2 pk = { f2bf2(a[0] + bvc, a[1] + bvc), f2bf2(a[2] + bvc, a[3] + bvc) };
      *(uint2*)(Vo + ((size_t)b * CCH + c) * NTOK + n0 + nt2 * 16 + hi * 4) = pk;
    }
  }
}

#define LD_K(dst, chk) do {                                                    \
  _Pragma("unroll")                                                            \
  for (int mt_ = 0; mt_ < 4; mt_++)                                            \
    dst[mt_] = *(const bf16x8*)(Kb + (size_t)((chk) * 64 + mt_ * 16 + lo) * CQK + hi * 8); \
} while (0)

// ---------------- Kernel 2: pipelined flash attention + residual ----------------
// R2 structure (512 thr / 8 waves / 64 q / grid 256), with: lgkm-only barrier
// (vmcnt never drains in the loop -> K/V prefetch spans chunks), l-sum folded
// into PV via ones-channel MFMA, setprio around softmax.
__global__ __launch_bounds__(512, 2) void attn(
    const float* __restrict__ x,
    const u16* __restrict__ Qm, const u16* __restrict__ Km,
    const u16* __restrict__ Vm, float* __restrict__ out)
{
  const int g   = blockIdx.x;
  const int lw3 = g & 7;
  const int b   = lw3 >> 1;                      // batch -> XCD pair
  const int qt  = ((g >> 3) << 1) | (lw3 & 1);
  const int q0  = qt * 64;

  const int tid  = threadIdx.x;
  const int w    = tid >> 6;
  const int lane = tid & 63;
  const int lo   = lane & 15;
  const int hi   = lane >> 4;

  __shared__ u16   P_lds[2][64][72];
  __shared__ float a_lds[2][64];
  __shared__ float l_lds[64];

  const f32x4 fz = { 0.f, 0.f, 0.f, 0.f };
  bfu onesu;
#pragma unroll
  for (int j = 0; j < 8; j++) onesu.s[j] = 0x3F80;
  const bf16x8 ones = onesu.v;

  bf16x8 qf = *(const bf16x8*)(Qm + ((size_t)b * NTOK + q0 + (w & 3) * 16 + lo) * CQK + hi * 8);

  f32x4 acc[4][2];
#pragma unroll
  for (int t = 0; t < 4; t++)
#pragma unroll
    for (int cj = 0; cj < 2; cj++) acc[t][cj] = fz;
  f32x4 acc_l = fz;               // l rides PV as a ones-channel
  float m_run = -INFINITY;

  const int  c0 = w * 32;
  const u16* Vb = Vm + (size_t)b * CCH * NTOK;
  const u16* Kb = Km + (size_t)b * NTOK * CQK;

  bf16x8 kf_cur[4], kf_nxt[4];

  // softmax for the chunk in kf_cur; P/alpha -> buffer nb. No l here.
  auto softmax_chunk = [&](int nb) {
    f32x4 s[4];
#pragma unroll
    for (int mt = 0; mt < 4; mt++) s[mt] = mfma16(kf_cur[mt], qf, fz);
    float cm = -INFINITY;
#pragma unroll
    for (int mt = 0; mt < 4; mt++)
#pragma unroll
      for (int r = 0; r < 4; r++) cm = fmaxf(cm, s[mt][r]);
    cm = fmaxf(cm, __shfl_xor(cm, 16));
    cm = fmaxf(cm, __shfl_xor(cm, 32));
    float mnew  = fmaxf(m_run, cm);
    float alpha = __builtin_amdgcn_exp2f(m_run - mnew);
    m_run = mnew;
    u32 pw[4][2];
#pragma unroll
    for (int mt = 0; mt < 4; mt++) {
      float p0 = __builtin_amdgcn_exp2f(s[mt][0] - mnew);
      float p1 = __builtin_amdgcn_exp2f(s[mt][1] - mnew);
      float p2 = __builtin_amdgcn_exp2f(s[mt][2] - mnew);
      float p3 = __builtin_amdgcn_exp2f(s[mt][3] - mnew);
      pw[mt][0] = f2bf2(p0, p1);
      pw[mt][1] = f2bf2(p2, p3);
    }
    u16* prow = &P_lds[nb][w * 16 + lo][0];
#pragma unroll
    for (int mt = 0; mt < 4; mt++) {
      *(u32*)(prow + mt * 16 + hi * 4)     = pw[mt][0];
      *(u32*)(prow + mt * 16 + hi * 4 + 2) = pw[mt][1];
    }
    if (lane < 16) a_lds[nb][w * 16 + lane] = alpha;
  };

  // Prologue: softmax(0) into buf 0; K(1) in kf_cur.
  if (w < 4) {
    LD_K(kf_cur, 0);
    softmax_chunk(0);
    LD_K(kf_cur, 1);
  }
  __syncthreads();

  for (int ch = 0; ch < 64; ch++) {
    const int    buf  = ch & 1;
    const size_t moff = (size_t)ch * 64;

    // All V fragments for chunk ch at top; stay in flight across the barrier.
    bf16x8 vf[2][2];
#pragma unroll
    for (int cj = 0; cj < 2; cj++)
#pragma unroll
      for (int mh = 0; mh < 2; mh++)
        vf[cj][mh] = *(const bf16x8*)(Vb + (size_t)(c0 + cj * 16 + lo) * NTOK + moff + mh * 32 + hi * 8);

    if (w < 4 && ch + 2 < 64) LD_K(kf_nxt, ch + 2);

    // LDS reads for PV(ch): issued early, consumed after softmax.
    f32x4 al[4];
#pragma unroll
    for (int t = 0; t < 4; t++) al[t] = *(f32x4*)&a_lds[buf][t * 16 + hi * 4];
    bf16x8 af[4][2];
#pragma unroll
    for (int t = 0; t < 4; t++)
#pragma unroll
      for (int mh = 0; mh < 2; mh++)
        af[t][mh] = *(const bf16x8*)(&P_lds[buf][t * 16 + lo][mh * 32 + hi * 8]);

    // Softmax-wave extras: own P row + own alpha (rows 4hi+r of q-tile w).
    bf16x8 afl0, afl1;
    f32x4  all;
    if (w < 4) {
      afl0 = *(const bf16x8*)(&P_lds[buf][w * 16 + lo][hi * 8]);
      afl1 = *(const bf16x8*)(&P_lds[buf][w * 16 + lo][32 + hi * 8]);
      all  = *(f32x4*)&a_lds[buf][w * 16 + hi * 4];
    }

    if (w < 4 && ch + 1 < 64) {
      __builtin_amdgcn_s_setprio(1);
      softmax_chunk(buf ^ 1);
      __builtin_amdgcn_s_setprio(0);
    }

    // Rescale + PV(ch).
#pragma unroll
    for (int t = 0; t < 4; t++)
#pragma unroll
      for (int cj = 0; cj < 2; cj++) {
        acc[t][cj][0] *= al[t][0]; acc[t][cj][1] *= al[t][1];
        acc[t][cj][2] *= al[t][2]; acc[t][cj][3] *= al[t][3];
      }
#pragma unroll
    for (int t = 0; t < 4; t++)
#pragma unroll
      for (int cj = 0; cj < 2; cj++)
#pragma unroll
        for (int mh = 0; mh < 2; mh++)
          acc[t][cj] = mfma16(af[t][mh], vf[cj][mh], acc[t][cj]);

    if (w < 4) {
      acc_l[0] *= all[0]; acc_l[1] *= all[1];
      acc_l[2] *= all[2]; acc_l[3] *= all[3];
      acc_l = mfma16(afl0, ones, acc_l);
      acc_l = mfma16(afl1, ones, acc_l);
#pragma unroll
      for (int mt = 0; mt < 4; mt++) kf_cur[mt] = kf_nxt[mt];
    }

    // lgkm-only barrier: P/alpha visible, global prefetch NOT drained.
    asm volatile("s_waitcnt lgkmcnt(0)" ::: "memory");
    __builtin_amdgcn_s_barrier();
  }

  // Final l per query (ones-channel acc): row q = w*16 + 4hi + r, any col.
  if (w < 4 && lo == 0) {
#pragma unroll
    for (int j = 0; j < 4; j++) l_lds[w * 16 + hi * 4 + j] = acc_l[j];
  }
  __syncthreads();

  const float* xb2 = x   + (size_t)b * CCH * NTOK;
  float*       ob  = out + (size_t)b * CCH * NTOK;
#pragma unroll
  for (int t = 0; t < 4; t++) {
    f32x4 lv = *(f32x4*)&l_lds[t * 16 + hi * 4];
    float il0 = 1.f / lv[0], il1 = 1.f / lv[1], il2 = 1.f / lv[2], il3 = 1.f / lv[3];
#pragma unroll
    for (int cj = 0; cj < 2; cj++) {
      int c = c0 + cj * 16 + lo;
      size_t base = (size_t)c * NTOK + q0 + t * 16 + hi * 4;
      float4 xr = *(const float4*)(xb2 + base);
      float4 o;
      o.x = acc[t][cj][0] * il0 + xr.x;
      o.y = acc[t][cj][1] * il1 + xr.y;
      o.z = acc[t][cj][2] * il2 + xr.z;
      o.w = acc[t][cj][3] * il3 + xr.w;
      *(float4*)(ob + base) = o;
    }
  }
}

extern "C" void kernel_launch(void* const* d_in, const int* in_sizes, int n_in,
                              void* d_out, int out_size, void* d_ws, size_t ws_size,
                              hipStream_t stream) {
  const float* x  = (const float*)d_in[0];
  const float* wq = (const float*)d_in[1];
  const float* bq = (const float*)d_in[2];
  const float* wk = (const float*)d_in[3];
  const float* bk = (const float*)d_in[4];
  const float* wv = (const float*)d_in[5];
  const float* bv = (const float*)d_in[6];
  float* out = (float*)d_out;

  // ws (bf16): Q [4,4096,32] | K [4,4096,32] | V [4,256,4096] | Whi,Wlo [320,256]
  u16* Qp  = (u16*)d_ws;
  u16* Kp  = Qp + (size_t)NB * NTOK * CQK;
  u16* Vp  = Kp + (size_t)NB * NTOK * CQK;
  u16* Whi = Vp + (size_t)NB * CCH * NTOK;
  u16* Wlo = Whi + (size_t)320 * CCH;

  convert_w<<<80, 256, 0, stream>>>(wq, wk, wv, Whi, Wlo);
  dim3 pg(128, NB);
  qkv_proj<<<pg, 256, 0, stream>>>(x, bq, bk, bv, Whi, Wlo, Qp, Kp, Vp);
  attn<<<256, 512, 0, stream>>>(x, Qp, Kp, Vp, out);
}